// Round 1
// baseline (31442.905 us; speedup 1.0000x reference)
//
#include <hip/hip_runtime.h>

#define BATCH 128
#define SEQ   1024
#define INSZ  128
#define HID   256
#define FAN   384
#define NBLK  256
#define NTHR  256
#define EPSV  1e-5f

typedef __attribute__((ext_vector_type(4))) float f32x4;
typedef __attribute__((ext_vector_type(8))) short short8;

__device__ __forceinline__ unsigned short f2bf(float f) {
  unsigned u = __builtin_bit_cast(unsigned, f);
  u += 0x7FFFu + ((u >> 16) & 1u);          // round-to-nearest-even
  return (unsigned short)(u >> 16);
}

__launch_bounds__(NTHR)
__global__ void bnlstm_kernel(const float* __restrict__ x,
                              const float* __restrict__ W,
                              const float* __restrict__ gamma,
                              const float* __restrict__ beta,
                              float* __restrict__ out,
                              unsigned short* __restrict__ hbuf,   // [2][128][256] bf16
                              unsigned* __restrict__ barcnt) {
  // LDS: one K-chunk of A = [x_t | h] in bf16, padded row stride 136 (=128+8)
  __shared__ unsigned short Z[BATCH][136];
  __shared__ float red1[4][16];
  __shared__ float red2[4][16];
  __shared__ float sc_sh[16], sh_sh[16];
  __shared__ float gn_sh[BATCH][5];          // stride 5 -> 2-way LDS conflicts only

  const int tid  = threadIdx.x;
  const int bid  = blockIdx.x;
  // XCD-aware j mapping: XCD (bid%8) owns contiguous j range -> full-line L2 merges on out[]
  const int j    = (bid & 7) * 32 + (bid >> 3);
  const int lane = tid & 63;
  const int w    = tid >> 6;                 // wave id 0..3
  const int col  = lane & 15;                // MFMA: A-row-in-tile == C-col == lane&15
  const int kg   = lane >> 4;                // k-group 0..3

  // ---- load this block's W columns (gates k=0..3 of feature j) as B-fragments ----
  // B-frag layout (16x16x32): lane holds B[k = kg*8 + e][col], cols >=4 are zero pad.
  short8 wf[12];
  {
    const int c = col * HID + j;
    for (int kt = 0; kt < 12; ++kt) {
      short8 v;
      for (int e = 0; e < 8; ++e) {
        int r = kt * 32 + kg * 8 + e;
        float val = (col < 4) ? W[r * 1024 + c] : 0.f;
        v[e] = (short)f2bf(val);
      }
      wf[kt] = v;
    }
  }
  // NOTE: bias b is skipped — BN subtracts the batch mean, which cancels it exactly.

  float c_reg = 0.f;                         // c-state for b=tid (threads tid<128)
  unsigned tgt = 0;

  for (int t = 0; t < SEQ; ++t) {
    f32x4 acc0 = {0.f, 0.f, 0.f, 0.f};
    f32x4 acc1 = {0.f, 0.f, 0.f, 0.f};
    const int p = t & 1;
    const int nch = (t == 0) ? 1 : 3;        // h0 == 0: skip h chunks at t=0

    for (int c = 0; c < nch; ++c) {
      // ---- stage one 128-wide K chunk into LDS (bf16) ----
      if (c == 0) {                          // x_t (fp32 -> bf16)
        #pragma unroll 4
        for (int e = tid; e < 4096; e += NTHR) {
          int b = e >> 5, q = e & 31;
          const float4 f = *(const float4*)&x[((size_t)b * SEQ + t) * INSZ + q * 4];
          ushort4 s;
          s.x = f2bf(f.x); s.y = f2bf(f.y); s.z = f2bf(f.z); s.w = f2bf(f.w);
          *(ushort4*)&Z[b][q * 4] = s;
        }
      } else {                               // h (already bf16)
        const unsigned short* hsrc = hbuf + p * (BATCH * HID) + (c - 1) * 128;
        #pragma unroll 4
        for (int e = tid; e < 2048; e += NTHR) {
          int b = e >> 4, q = e & 15;
          uint4 v = *(const uint4*)&hsrc[b * HID + q * 8];
          *(uint4*)&Z[b][q * 8] = v;
        }
      }
      __syncthreads();

      // ---- MFMA: 2 M-tiles per wave, 4 K-tiles per chunk ----
      #pragma unroll
      for (int ktl = 0; ktl < 4; ++ktl) {
        short8 bf = wf[c * 4 + ktl];
        const int kloc = ktl * 32 + kg * 8;
        {
          short8 af = *(const short8*)&Z[(2 * w) * 16 + col][kloc];
          acc0 = __builtin_amdgcn_mfma_f32_16x16x32_bf16(af, bf, acc0, 0, 0, 0);
        }
        {
          short8 af = *(const short8*)&Z[(2 * w + 1) * 16 + col][kloc];
          acc1 = __builtin_amdgcn_mfma_f32_16x16x32_bf16(af, bf, acc1, 0, 0, 0);
        }
      }
      __syncthreads();
    }

    // ---- BN stats: sum / sumsq over batch per column (block-local) ----
    float s1 = 0.f, s2 = 0.f;
    #pragma unroll
    for (int i = 0; i < 4; ++i) { s1 += acc0[i]; s2 += acc0[i] * acc0[i]; }
    #pragma unroll
    for (int i = 0; i < 4; ++i) { s1 += acc1[i]; s2 += acc1[i] * acc1[i]; }
    s1 += __shfl_xor(s1, 16); s2 += __shfl_xor(s2, 16);   // same col, other rows
    s1 += __shfl_xor(s1, 32); s2 += __shfl_xor(s2, 32);
    if (lane < 16) { red1[w][lane] = s1; red2[w][lane] = s2; }
    __syncthreads();

    if (tid < 16) {
      float S1 = red1[0][tid] + red1[1][tid] + red1[2][tid] + red1[3][tid];
      float S2 = red2[0][tid] + red2[1][tid] + red2[2][tid] + red2[3][tid];
      float mean = S1 * (1.f / BATCH);
      float var  = S2 * (1.f / BATCH) - mean * mean;
      var = fmaxf(var, 0.f);
      float rstd = rsqrtf(var + EPSV);
      float gam = 1.f, bet = 0.f;
      if (tid < 4) { gam = gamma[tid * HID + j]; bet = beta[tid * HID + j]; }
      float sc = rstd * gam;
      sc_sh[tid] = sc;
      sh_sh[tid] = bet - mean * sc;
    }
    __syncthreads();

    // ---- normalize, exchange gates via LDS so one thread owns (b, all 4 gates) ----
    {
      const float sc = sc_sh[col], sh = sh_sh[col];
      if (col < 4) {
        #pragma unroll
        for (int m = 0; m < 2; ++m) {
          f32x4 a = m ? acc1 : acc0;
          int rb = (2 * w + m) * 16 + kg * 4;   // C layout: row = kg*4 + i
          #pragma unroll
          for (int i = 0; i < 4; ++i) gn_sh[rb + i][col] = a[i] * sc + sh;
        }
      }
    }
    __syncthreads();

    if (tid < BATCH) {
      const int b = tid;
      float iv = gn_sh[b][0], fv = gn_sh[b][1], gv = gn_sh[b][2], ov = gn_sh[b][3];
      float ig = 1.f / (1.f + __expf(-iv));
      float fg = 1.f / (1.f + __expf(-fv));
      float gg = tanhf(gv);
      float og = 1.f / (1.f + __expf(-ov));
      float cn = fg * c_reg + ig * gg;
      float hn = og * tanhf(cn);
      c_reg = cn;
      out[((size_t)b * SEQ + t) * HID + j] = hn;
      hbuf[(p ^ 1) * (BATCH * HID) + b * HID + j] = f2bf(hn);
      if (t == SEQ - 1) {
        out[(size_t)BATCH * SEQ * HID + b * HID + j] = hn;                 // hy
        out[(size_t)BATCH * SEQ * HID + BATCH * HID + b * HID + j] = cn;   // cy
      }
    }

    // ---- one grid barrier per step (monotonic counter; release/acquire fences) ----
    if (t < SEQ - 1) {
      __syncthreads();                        // drains all threads' vmem (vmcnt 0)
      if (tid == 0) {
        __threadfence();                      // L2 writeback (release, agent scope)
        tgt += NBLK;
        atomicAdd(barcnt, 1u);
        while (__hip_atomic_load(barcnt, __ATOMIC_RELAXED, __HIP_MEMORY_SCOPE_AGENT) < tgt) {
          __builtin_amdgcn_s_sleep(2);
        }
        __threadfence();                      // L2 invalidate (acquire)
      }
      __syncthreads();
    }
  }
}

extern "C" void kernel_launch(void* const* d_in, const int* in_sizes, int n_in,
                              void* d_out, int out_size, void* d_ws, size_t ws_size,
                              hipStream_t stream) {
  const float* x     = (const float*)d_in[0];
  const float* W     = (const float*)d_in[1];
  // d_in[2] = bias: mathematically cancelled by BatchNorm, unused.
  const float* gamma = (const float*)d_in[3];
  const float* beta  = (const float*)d_in[4];
  float* out = (float*)d_out;

  unsigned* barcnt = (unsigned*)d_ws;
  unsigned short* hbuf = (unsigned short*)((char*)d_ws + 256);

  hipMemsetAsync(d_ws, 0, 256, stream);       // reset barrier counter each call
  hipLaunchKernelGGL(bnlstm_kernel, dim3(NBLK), dim3(NTHR), 0, stream,
                     x, W, gamma, beta, out, hbuf, barcnt);
}

// Round 2
// 7184.151 us; speedup vs baseline: 4.3767x; 4.3767x over previous
//
#include <hip/hip_runtime.h>

#define BATCH 128
#define SEQ   1024
#define INSZ  128
#define HID   256
#define KTOT  384          // INSZ + HID
#define NBLK  64
#define NTHR  512
#define EPSV  1e-5f

typedef __attribute__((ext_vector_type(4))) float f32x4;
typedef __attribute__((ext_vector_type(8))) short short8;
typedef unsigned long long u64;

__device__ __forceinline__ unsigned short f2bf(float f) {
  unsigned u = __builtin_bit_cast(unsigned, f);
  u += 0x7FFFu + ((u >> 16) & 1u);          // round-to-nearest-even
  return (unsigned short)(u >> 16);
}
__device__ __forceinline__ u64 pack2f(float a, float b) {
  return ((u64)__builtin_bit_cast(unsigned, b) << 32) | __builtin_bit_cast(unsigned, a);
}

// All recurrence traffic is agent-scope (sc1, L2-bypass): no wbl2/inv fences needed,
// L2 never holds stale or dirty recurrence data. out[] also write-through so the
// only dirty lines ever are the final hy/cy (flushed at kernel end).
__device__ __forceinline__ u64 cload(const void* p) {
  return __hip_atomic_load((const u64*)p, __ATOMIC_RELAXED, __HIP_MEMORY_SCOPE_AGENT);
}
__device__ __forceinline__ void cstore(void* p, u64 v) {
  __hip_atomic_store((u64*)p, v, __ATOMIC_RELAXED, __HIP_MEMORY_SCOPE_AGENT);
}

__launch_bounds__(NTHR)
__global__ void bnlstm_kernel(const float* __restrict__ x,
                              const float* __restrict__ W,
                              const float* __restrict__ gamma,
                              const float* __restrict__ beta,
                              float* __restrict__ out,
                              unsigned short* __restrict__ hbuf,   // [2][128][256] bf16
                              unsigned* __restrict__ barcnt) {
  // A = [x_t | h] staged bf16, XOR-swizzled: elem (b, 8-group g) lives at
  // Zs[b*384 + ((g ^ (b&7))<<3)].  Row = 768B = 6*128B, so without the swizzle
  // all 16 A-frag rows of an MFMA read hit the same bank-quad (round-1's 2.3e8
  // conflicts); with it, 2-way = free.
  __shared__ unsigned short Zs[BATCH * KTOT];        // 96 KB
  __shared__ float red1[8][16];
  __shared__ float red2[8][16];
  __shared__ float sc_sh[16], sh_sh[16];
  __shared__ float gn_sh[BATCH * 17];                // stride 17: 2-way reads

  const int tid  = threadIdx.x;
  const int bid  = blockIdx.x;
  // XCD-aware: XCD (bid&7) owns a contiguous 32-feature j range.
  const int jbase = (bid & 7) * 32 + (bid >> 3) * 4;
  const int lane = tid & 63;
  const int wid  = tid >> 6;                // 8 waves, wave = one 16-row M-tile
  const int col  = lane & 15;
  const int kg   = lane >> 4;

  // ---- B fragments: 16 real cols = (jsub, gate), col = jsub*4 + gate ----
  short8 wf[12];
  {
    const int wcol = (col & 3) * HID + jbase + (col >> 2);
    for (int kt = 0; kt < 12; ++kt) {
      short8 v;
      for (int e = 0; e < 8; ++e)
        v[e] = (short)f2bf(W[(kt * 32 + kg * 8 + e) * 1024 + wcol]);
      wf[kt] = v;
    }
  }
  float gam = 1.f, bet = 0.f;
  if (tid < 16) {
    gam = gamma[(tid & 3) * HID + jbase + (tid >> 2)];
    bet = beta [(tid & 3) * HID + jbase + (tid >> 2)];
  }
  // bias input is skipped: BN subtracts the batch mean, cancelling it exactly.

  float cst[4] = {0.f, 0.f, 0.f, 0.f};      // c-state, threads tid<128 own batch row tid
  unsigned tgt = 0;

  // x prefetch registers: 2048 16B-groups per step / 512 threads = 4 iters x 2 float4
  float4 xp[8];
  {
    #pragma unroll
    for (int it = 0; it < 4; ++it) {
      int e = tid + it * NTHR, b = e >> 4, q = e & 15;
      const float* px = &x[((size_t)b * SEQ + 0) * INSZ + q * 8];
      xp[it * 2]     = *(const float4*)px;
      xp[it * 2 + 1] = *(const float4*)(px + 4);
    }
  }

  for (int t = 0; t < SEQ; ++t) {
    // ---- stage x chunk (groups 0..15 of each row) from prefetch regs ----
    #pragma unroll
    for (int it = 0; it < 4; ++it) {
      int e = tid + it * NTHR, b = e >> 4, q = e & 15;
      float4 f0 = xp[it * 2], f1 = xp[it * 2 + 1];
      uint4 s;
      s.x = f2bf(f0.x) | ((unsigned)f2bf(f0.y) << 16);
      s.y = f2bf(f0.z) | ((unsigned)f2bf(f0.w) << 16);
      s.z = f2bf(f1.x) | ((unsigned)f2bf(f1.y) << 16);
      s.w = f2bf(f1.z) | ((unsigned)f2bf(f1.w) << 16);
      *(uint4*)&Zs[b * KTOT + ((q ^ (b & 7)) << 3)] = s;
    }
    // ---- stage h chunk (groups 16..47) via coherent loads (or zeros at t=0) ----
    if (t == 0) {
      #pragma unroll
      for (int it = 0; it < 8; ++it) {
        int e = tid + it * NTHR, b = e >> 5, q = e & 31;
        int g = (16 + q) ^ (b & 7);
        *(u64*)&Zs[b * KTOT + g * 8]     = 0;
        *(u64*)&Zs[b * KTOT + g * 8 + 4] = 0;
      }
    } else {
      const unsigned short* hsrc = hbuf + (t & 1) * (BATCH * HID);
      #pragma unroll
      for (int it = 0; it < 8; ++it) {
        int e = tid + it * NTHR, b = e >> 5, q = e & 31;
        u64 v0 = cload(&hsrc[b * HID + q * 8]);
        u64 v1 = cload(&hsrc[b * HID + q * 8 + 4]);
        int g = (16 + q) ^ (b & 7);
        *(u64*)&Zs[b * KTOT + g * 8]     = v0;
        *(u64*)&Zs[b * KTOT + g * 8 + 4] = v1;
      }
    }
    __syncthreads();

    // ---- prefetch x(t+1) while MFMA/BN/gates/barrier run ----
    {
      int tn = (t < SEQ - 1) ? t + 1 : t;
      #pragma unroll
      for (int it = 0; it < 4; ++it) {
        int e = tid + it * NTHR, b = e >> 4, q = e & 15;
        const float* px = &x[((size_t)b * SEQ + tn) * INSZ + q * 8];
        xp[it * 2]     = *(const float4*)px;
        xp[it * 2 + 1] = *(const float4*)(px + 4);
      }
    }

    // ---- GEMM: wave wid computes M-tile rows [wid*16, wid*16+16) x 16 cols ----
    f32x4 acc = {0.f, 0.f, 0.f, 0.f};
    {
      const int arow = wid * 16 + col;
      const unsigned short* zrow = &Zs[arow * KTOT];
      const int swz = arow & 7;
      #pragma unroll
      for (int kt = 0; kt < 12; ++kt) {
        short8 af = *(const short8*)&zrow[((kt * 4 + kg) ^ swz) << 3];
        acc = __builtin_amdgcn_mfma_f32_16x16x32_bf16(af, wf[kt], acc, 0, 0, 0);
      }
    }

    // ---- BN stats: per-col sum/sumsq over all 128 batch rows ----
    float s1 = 0.f, s2 = 0.f;
    #pragma unroll
    for (int i = 0; i < 4; ++i) { s1 += acc[i]; s2 += acc[i] * acc[i]; }
    s1 += __shfl_xor(s1, 16); s2 += __shfl_xor(s2, 16);
    s1 += __shfl_xor(s1, 32); s2 += __shfl_xor(s2, 32);
    if (lane < 16) { red1[wid][lane] = s1; red2[wid][lane] = s2; }
    __syncthreads();

    if (tid < 16) {
      float S1 = 0.f, S2 = 0.f;
      #pragma unroll
      for (int w2 = 0; w2 < 8; ++w2) { S1 += red1[w2][tid]; S2 += red2[w2][tid]; }
      float mean = S1 * (1.f / BATCH);
      float var  = fmaxf(S2 * (1.f / BATCH) - mean * mean, 0.f);
      float sc = rsqrtf(var + EPSV) * gam;
      sc_sh[tid] = sc;
      sh_sh[tid] = bet - mean * sc;
    }
    __syncthreads();

    // ---- normalize into gn_sh[b][col] (stride 17) ----
    {
      const float sc = sc_sh[col], sh = sh_sh[col];
      const int rb = wid * 16 + kg * 4;     // C layout: row = kg*4 + i
      #pragma unroll
      for (int i = 0; i < 4; ++i) gn_sh[(rb + i) * 17 + col] = acc[i] * sc + sh;
    }
    __syncthreads();

    // ---- LSTM gates: thread b<128 owns batch row b, all 4 features ----
    if (tid < BATCH) {
      float hn[4];
      #pragma unroll
      for (int js = 0; js < 4; ++js) {
        float iv = gn_sh[tid * 17 + js * 4 + 0];
        float fv = gn_sh[tid * 17 + js * 4 + 1];
        float gv = gn_sh[tid * 17 + js * 4 + 2];
        float ov = gn_sh[tid * 17 + js * 4 + 3];
        float ig = 1.f / (1.f + __expf(-iv));
        float fg = 1.f / (1.f + __expf(-fv));
        float gg = tanhf(gv);
        float og = 1.f / (1.f + __expf(-ov));
        float cn = fg * cst[js] + ig * gg;
        cst[js] = cn;
        hn[js] = og * tanhf(cn);
      }
      float* po = &out[((size_t)tid * SEQ + t) * HID + jbase];
      cstore(po,     pack2f(hn[0], hn[1]));
      cstore(po + 2, pack2f(hn[2], hn[3]));
      u64 hb = (u64)f2bf(hn[0]) | ((u64)f2bf(hn[1]) << 16) |
               ((u64)f2bf(hn[2]) << 32) | ((u64)f2bf(hn[3]) << 48);
      cstore(&hbuf[((t & 1) ^ 1) * (BATCH * HID) + tid * HID + jbase], hb);
      if (t == SEQ - 1) {
        float* ph = &out[(size_t)BATCH * SEQ * HID + (size_t)tid * HID + jbase];
        float* pc = ph + BATCH * HID;
        #pragma unroll
        for (int js = 0; js < 4; ++js) { ph[js] = hn[js]; pc[js] = cst[js]; }
      }
    }

    // ---- grid barrier: syncthreads drains each wave's vmcnt -> stores visible ----
    if (t < SEQ - 1) {
      __syncthreads();
      if (tid == 0) {
        tgt += NBLK;
        __hip_atomic_fetch_add(barcnt, 1u, __ATOMIC_RELAXED, __HIP_MEMORY_SCOPE_AGENT);
        while (__hip_atomic_load(barcnt, __ATOMIC_RELAXED, __HIP_MEMORY_SCOPE_AGENT) < tgt)
          __builtin_amdgcn_s_sleep(2);
      }
      __syncthreads();
    }
  }
}

extern "C" void kernel_launch(void* const* d_in, const int* in_sizes, int n_in,
                              void* d_out, int out_size, void* d_ws, size_t ws_size,
                              hipStream_t stream) {
  const float* x     = (const float*)d_in[0];
  const float* W     = (const float*)d_in[1];
  // d_in[2] = bias: cancelled by BatchNorm, unused.
  const float* gamma = (const float*)d_in[3];
  const float* beta  = (const float*)d_in[4];
  float* out = (float*)d_out;

  unsigned* barcnt = (unsigned*)d_ws;
  unsigned short* hbuf = (unsigned short*)((char*)d_ws + 256);

  hipMemsetAsync(d_ws, 0, 256, stream);       // reset barrier counter each call
  hipLaunchKernelGGL(bnlstm_kernel, dim3(NBLK), dim3(NTHR), 0, stream,
                     x, W, gamma, beta, out, hbuf, barcnt);
}

// Round 3
// 6661.478 us; speedup vs baseline: 4.7201x; 1.0785x over previous
//
#include <hip/hip_runtime.h>

#define BATCH 128
#define SEQ   1024
#define INSZ  128
#define HID   256
#define NBLK  32
#define NTHR  512
#define FPB   8            // features per block
#define EPSV  1e-5f

typedef __attribute__((ext_vector_type(4))) float f32x4;
typedef __attribute__((ext_vector_type(8))) short short8;
typedef unsigned long long u64;

__device__ __forceinline__ unsigned short f2bf(float f) {
  unsigned u = __builtin_bit_cast(unsigned, f);
  u += 0x7FFFu + ((u >> 16) & 1u);          // round-to-nearest-even
  return (unsigned short)(u >> 16);
}
__device__ __forceinline__ u64 cload64(const void* p) {
  return __hip_atomic_load((const u64*)p, __ATOMIC_RELAXED, __HIP_MEMORY_SCOPE_AGENT);
}

__launch_bounds__(NTHR)
__global__ void bnlstm_kernel(const float* __restrict__ x,
                              const float* __restrict__ W,
                              const float* __restrict__ gamma,
                              const float* __restrict__ beta,
                              float* __restrict__ out,
                              unsigned short* __restrict__ hbuf,   // [2][32 g][128 b][8 e] bf16
                              unsigned* __restrict__ flags) {      // [32] at 128B stride
  // A = [x | h] in column-major 16B units: Zs[g][b] (g = K-group 0..47, b = row).
  // MFMA A-frag read = 16 consecutive rows -> contiguous 256B -> conflict-free, no swizzle.
  __shared__ __attribute__((aligned(16))) unsigned short Zs[48 * 128 * 8];   // 96 KB
  __shared__ float red1[8][32];
  __shared__ float red2[8][32];
  __shared__ float waveTr[8][16][17];              // per-wave gate transpose scratch

  const int tid   = threadIdx.x;
  const int bid   = blockIdx.x;
  const int lane  = tid & 63;
  const int wid   = tid >> 6;                     // 8 waves, wave = one 16-row M-tile
  const int col16 = lane & 15;
  const int kg    = lane >> 4;
  const int d     = col16 & 3;                    // gate slot within col quad
  const int q     = col16 >> 2;                   // jsub within col-group

  // ---- B fragments in registers: 32 cols = (j_local 0..7) x (gate 0..3) ----
  // col c32 = cg*16+col16 ; gate = c32&3 ; j_local = c32>>2
  short8 wf[2][12];
  for (int cg = 0; cg < 2; ++cg) {
    const int c32 = cg * 16 + col16;
    const int wcol = (c32 & 3) * HID + bid * FPB + (c32 >> 2);
    for (int kt = 0; kt < 12; ++kt) {
      short8 v;
      for (int e = 0; e < 8; ++e)
        v[e] = (short)f2bf(W[(kt * 32 + kg * 8 + e) * 1024 + wcol]);
      wf[cg][kt] = v;
    }
  }
  // per-lane gamma/beta for BN finalize (col = lane, valid for lane<32; others unused)
  float gam = 0.f, bet = 0.f;
  if (lane < 32) {
    gam = gamma[(lane & 3) * HID + bid * FPB + (lane >> 2)];
    bet = beta [(lane & 3) * HID + bid * FPB + (lane >> 2)];
  }
  // bias input is skipped: BN subtracts the batch mean, cancelling it exactly.

  const int xb = tid & 127;                       // staging: row owned by this thread
  const int gb = tid >> 7;                        // staging: K-group stride base 0..3

  float cst[2] = {0.f, 0.f};                      // c-state per col-group
  float4 xp[8];                                   // x(t) prefetch (4 units x 32B)
  {
    #pragma unroll
    for (int k = 0; k < 4; ++k) {
      const float* px = &x[((size_t)xb * SEQ + 0) * INSZ + (gb + k * 4) * 8];
      xp[2 * k]     = *(const float4*)px;
      xp[2 * k + 1] = *(const float4*)(px + 4);
    }
  }

  for (int t = 0; t < SEQ; ++t) {
    const int pR = t & 1, pW = pR ^ 1;

    // ---- stage h: coherent 8B loads (IC) -> LDS, conflict-free writes ----
    {
      const unsigned short* hsrc = hbuf + pR * 32768;
      #pragma unroll
      for (int k = 0; k < 8; ++k) {
        const int gh = gb + k * 4;                // 0..31
        u64 v0 = cload64(&hsrc[(gh * 128 + xb) * 8]);
        u64 v1 = cload64(&hsrc[(gh * 128 + xb) * 8 + 4]);
        *(u64*)&Zs[((16 + gh) * 128 + xb) * 8]     = v0;
        *(u64*)&Zs[((16 + gh) * 128 + xb) * 8 + 4] = v1;
      }
    }
    // ---- stage x from prefetch regs (fp32 -> bf16 pack) ----
    #pragma unroll
    for (int k = 0; k < 4; ++k) {
      float4 f0 = xp[2 * k], f1 = xp[2 * k + 1];
      uint4 s;
      s.x = f2bf(f0.x) | ((unsigned)f2bf(f0.y) << 16);
      s.y = f2bf(f0.z) | ((unsigned)f2bf(f0.w) << 16);
      s.z = f2bf(f1.x) | ((unsigned)f2bf(f1.y) << 16);
      s.w = f2bf(f1.z) | ((unsigned)f2bf(f1.w) << 16);
      *(uint4*)&Zs[((gb + k * 4) * 128 + xb) * 8] = s;
    }
    __syncthreads();                              // s1: staging visible

    // ---- GEMM: wave = M-tile, 2 col-groups, B in regs, A shared across cgs ----
    f32x4 acc0 = {0.f, 0.f, 0.f, 0.f}, acc1 = {0.f, 0.f, 0.f, 0.f};
    {
      const int arow = wid * 16 + col16;
      #pragma unroll
      for (int kt = 0; kt < 12; ++kt) {
        short8 af = *(const short8*)&Zs[((kt * 4 + kg) * 128 + arow) * 8];
        acc0 = __builtin_amdgcn_mfma_f32_16x16x32_bf16(af, wf[0][kt], acc0, 0, 0, 0);
        acc1 = __builtin_amdgcn_mfma_f32_16x16x32_bf16(af, wf[1][kt], acc1, 0, 0, 0);
      }
    }

    // ---- BN partial sums (per wave) ----
    {
      float a1 = acc0[0] + acc0[1] + acc0[2] + acc0[3];
      float b1 = acc0[0]*acc0[0] + acc0[1]*acc0[1] + acc0[2]*acc0[2] + acc0[3]*acc0[3];
      float a2 = acc1[0] + acc1[1] + acc1[2] + acc1[3];
      float b2 = acc1[0]*acc1[0] + acc1[1]*acc1[1] + acc1[2]*acc1[2] + acc1[3]*acc1[3];
      a1 += __shfl_xor(a1, 16); b1 += __shfl_xor(b1, 16);
      a1 += __shfl_xor(a1, 32); b1 += __shfl_xor(b1, 32);
      a2 += __shfl_xor(a2, 16); b2 += __shfl_xor(b2, 16);
      a2 += __shfl_xor(a2, 32); b2 += __shfl_xor(b2, 32);
      if (lane < 16) {
        red1[wid][lane] = a1;      red2[wid][lane] = b1;
        red1[wid][16 + lane] = a2; red2[wid][16 + lane] = b2;
      }
    }
    __syncthreads();                              // s2: partials visible

    // ---- prefetch x(t+1): latency hides under BN finalize + gates ----
    {
      const int tn = (t + 1 < SEQ) ? t + 1 : t;
      #pragma unroll
      for (int k = 0; k < 4; ++k) {
        const float* px = &x[((size_t)xb * SEQ + tn) * INSZ + (gb + k * 4) * 8];
        xp[2 * k]     = *(const float4*)px;
        xp[2 * k + 1] = *(const float4*)(px + 4);
      }
    }

    // ---- BN finalize: every wave computes all 32 cols redundantly (no barrier) ----
    float sc0, sh0, sc1v, sh1v;
    {
      const int cidx = lane & 31;
      float S1 = 0.f, S2 = 0.f;
      #pragma unroll
      for (int w2 = 0; w2 < 8; ++w2) { S1 += red1[w2][cidx]; S2 += red2[w2][cidx]; }
      float mean = S1 * (1.f / BATCH);
      float var  = fmaxf(S2 * (1.f / BATCH) - mean * mean, 0.f);
      float scl = rsqrtf(var + EPSV) * gam;
      float shl = bet - mean * scl;
      sc0  = __shfl(scl, col16);       sh0  = __shfl(shl, col16);
      sc1v = __shfl(scl, 16 + col16);  sh1v = __shfl(shl, 16 + col16);
    }

    // ---- normalize + intra-wave transpose + gates (all 8 waves busy) ----
    const int brow = wid * 16 + kg * 4 + d;
    #pragma unroll
    for (int cg = 0; cg < 2; ++cg) {
      f32x4 a = cg ? acc1 : acc0;
      const float sc = cg ? sc1v : sc0, sh = cg ? sh1v : sh0;
      #pragma unroll
      for (int i = 0; i < 4; ++i)
        waveTr[wid][kg * 4 + i][col16] = a[i] * sc + sh;   // in-wave: no barrier needed
      float g0 = waveTr[wid][kg * 4 + d][q * 4 + 0];
      float g1 = waveTr[wid][kg * 4 + d][q * 4 + 1];
      float g2 = waveTr[wid][kg * 4 + d][q * 4 + 2];
      float g3 = waveTr[wid][kg * 4 + d][q * 4 + 3];
      float ig = __builtin_amdgcn_rcpf(1.f + __expf(-g0));
      float fg = __builtin_amdgcn_rcpf(1.f + __expf(-g1));
      float gg = 1.f - 2.f * __builtin_amdgcn_rcpf(__expf(2.f * g2) + 1.f);
      float og = __builtin_amdgcn_rcpf(1.f + __expf(-g3));
      float cn = fg * cst[cg] + ig * gg;
      float hn = og * (1.f - 2.f * __builtin_amdgcn_rcpf(__expf(2.f * cn) + 1.f));
      cst[cg] = cn;
      const int jl = cg * 4 + q;
      // out: plain cached store (never read cross-block; flushed at kernel end)
      out[((size_t)brow * SEQ + t) * HID + bid * FPB + jl] = hn;
      // h for next step: cross-XCD -> IC (agent scope)
      __hip_atomic_store(&hbuf[pW * 32768 + (bid * 128 + brow) * 8 + jl],
                         f2bf(hn), __ATOMIC_RELAXED, __HIP_MEMORY_SCOPE_AGENT);
      if (t == SEQ - 1) {
        float* ph = &out[(size_t)BATCH * SEQ * HID + (size_t)brow * HID + bid * FPB + jl];
        ph[0] = hn;                 // hy
        ph[BATCH * HID] = cn;       // cy
      }
    }

    // ---- flag barrier: parallel-detect, no RMW ----
    if (t < SEQ - 1) {
      __syncthreads();                            // s5: drains each wave's hbuf stores
      if (tid == 0)
        __hip_atomic_store(&flags[bid * 32], (unsigned)(t + 1),
                           __ATOMIC_RELAXED, __HIP_MEMORY_SCOPE_AGENT);
      if (wid == 0) {
        const unsigned tv = (unsigned)(t + 1);
        while (true) {
          unsigned v = (lane < NBLK)
            ? __hip_atomic_load(&flags[lane * 32], __ATOMIC_RELAXED, __HIP_MEMORY_SCOPE_AGENT)
            : tv;
          if (__all((int)(v >= tv))) break;
          __builtin_amdgcn_s_sleep(1);
        }
      }
      __syncthreads();                            // s6: release all waves
    }
  }
}

extern "C" void kernel_launch(void* const* d_in, const int* in_sizes, int n_in,
                              void* d_out, int out_size, void* d_ws, size_t ws_size,
                              hipStream_t stream) {
  const float* x     = (const float*)d_in[0];
  const float* W     = (const float*)d_in[1];
  // d_in[2] = bias: cancelled by BatchNorm, unused.
  const float* gamma = (const float*)d_in[3];
  const float* beta  = (const float*)d_in[4];
  float* out = (float*)d_out;

  unsigned* flags = (unsigned*)d_ws;                               // 4 KB
  unsigned short* hbuf = (unsigned short*)((char*)d_ws + 4096);    // 2 x 64 KB

  // reset flags + h parity-0 (read at t=0) each call
  hipMemsetAsync(d_ws, 0, 4096 + 65536, stream);
  hipLaunchKernelGGL(bnlstm_kernel, dim3(NBLK), dim3(NTHR), 0, stream,
                     x, W, gamma, beta, out, hbuf, flags);
}